// Round 1
// baseline (65.427 us; speedup 1.0000x reference)
//
#include <hip/hip_runtime.h>

// Problem constants (match reference setup_inputs exactly)
#define B_SZ     8
#define S_SZ     16384
#define D_SZ     512
#define BLK_TOK  128            // selection_block_size
#define TOPK     16             // top_k per block
#define NBLK     (S_SZ / BLK_TOK)   // 128 blocks per batch

// One workgroup (256 threads = 4 waves) handles one (batch, token-block):
//  Phase 1: score 128 tokens (dot with W, fp64 accumulate for exact ordering)
//  Phase 2: wave 0 performs 16 iterative argmax reductions (desc score,
//           tie -> lower index, matching jax.lax.top_k)
//  Phase 3: all waves gather the 16 selected rows to the output.
__global__ __launch_bounds__(256, 4) void token_select_kernel(
    const float* __restrict__ x,
    const float* __restrict__ W,
    float* __restrict__ out)
{
    const int blk  = blockIdx.x;       // 0..127
    const int b    = blockIdx.y;       // 0..7
    const int tid  = threadIdx.x;      // 0..255
    const int wave = tid >> 6;         // 0..3
    const int lane = tid & 63;

    __shared__ double s_score[BLK_TOK];   // 1 KiB
    __shared__ int    s_sel[TOPK];

    // W fragment per lane: elements [lane*4, lane*4+4) and [256+lane*4, ...)
    const float4* W4 = reinterpret_cast<const float4*>(W);
    const float4 w0 = W4[lane];
    const float4 w1 = W4[64 + lane];

    const float* xbase = x + ((size_t)b * S_SZ + (size_t)blk * BLK_TOK) * D_SZ;

    // ---- Phase 1: scoring. Wave w handles tokens [w*32, w*32+32). ----
    const int t0 = wave * 32;
    #pragma unroll 4
    for (int t = t0; t < t0 + 32; ++t) {
        const float4* row = reinterpret_cast<const float4*>(xbase + (size_t)t * D_SZ);
        const float4 a0 = row[lane];        // bytes [lane*16, +16)
        const float4 a1 = row[64 + lane];   // bytes [1024 + lane*16, +16)
        double acc = (double)a0.x * (double)w0.x + (double)a0.y * (double)w0.y
                   + (double)a0.z * (double)w0.z + (double)a0.w * (double)w0.w
                   + (double)a1.x * (double)w1.x + (double)a1.y * (double)w1.y
                   + (double)a1.z * (double)w1.z + (double)a1.w * (double)w1.w;
        // 64-lane butterfly reduce (double)
        #pragma unroll
        for (int m = 32; m >= 1; m >>= 1)
            acc += __shfl_xor(acc, m, 64);
        if (lane == 0) s_score[t] = acc;
    }
    __syncthreads();

    // ---- Phase 2: top-16 by iterative argmax (wave 0 only). ----
    if (wave == 0) {
        double sc0 = s_score[lane];
        double sc1 = s_score[lane + 64];
        #pragma unroll
        for (int k = 0; k < TOPK; ++k) {
            // local best of the lane's two candidates (tie -> lower index)
            double bs; int bi;
            if (sc0 >= sc1) { bs = sc0; bi = lane; }
            else            { bs = sc1; bi = lane + 64; }
            // wave-wide argmax with lower-index tie-break
            #pragma unroll
            for (int m = 32; m >= 1; m >>= 1) {
                const double os = __shfl_xor(bs, m, 64);
                const int    oi = __shfl_xor(bi, m, 64);
                if (os > bs || (os == bs && oi < bi)) { bs = os; bi = oi; }
            }
            // all lanes now agree on (bs, bi)
            if (lane == 0) s_sel[k] = bi;
            if (bi == lane)      sc0 = -INFINITY;
            if (bi == lane + 64) sc1 = -INFINITY;
        }
    }
    __syncthreads();

    // ---- Phase 3: gather 16 selected rows (512 floats each). ----
    float* outbase = out + (((size_t)b * NBLK + blk) * TOPK) * D_SZ;
    #pragma unroll
    for (int r = wave; r < TOPK; r += 4) {
        const int idx = s_sel[r];
        const float4* src = reinterpret_cast<const float4*>(xbase + (size_t)idx * D_SZ);
        float4*       dst = reinterpret_cast<float4*>(outbase + (size_t)r * D_SZ);
        dst[lane]      = src[lane];
        dst[64 + lane] = src[64 + lane];
    }
}

extern "C" void kernel_launch(void* const* d_in, const int* in_sizes, int n_in,
                              void* d_out, int out_size, void* d_ws, size_t ws_size,
                              hipStream_t stream) {
    const float* x = (const float*)d_in[0];   // [8, 16384, 512] fp32
    const float* W = (const float*)d_in[1];   // [1, 512] fp32
    // d_in[2] is the bias b (zeros; constant shift never changes top-k order
    // and scores are not part of the output, so it is irrelevant).
    float* out = (float*)d_out;               // [8, 2048, 512] fp32

    dim3 grid(NBLK, B_SZ);
    dim3 block(256);
    token_select_kernel<<<grid, block, 0, stream>>>(x, W, out);
}